// Round 5
// baseline (34.627 us; speedup 1.0000x reference)
//
#include <hip/hip_runtime.h>

// ---------------------------------------------------------------------------
// Clifford algebra Cl(3,1,0) geometric product, DIM = 16 blades (f32).
//   out[n][c] = sum_{i,j: i^j == c} sign(i,j) * a[n][i] * b[n][j]
//
// R5: conflict-free LDS swizzle + 2 tiles/wave for MLP.
//  - Globals fully coalesced (lane l <-> base + l*16B), as R4.
//  - LDS transpose buffer [64 rows][16 floats], stride 64 (16KB/wave).
//    Quarter q of row r lives at slot s = (q + r + (r>>2)) & 3.
//    Verified: every 8-lane phase of every b128 access (g-order write,
//    row-order read, and the two out phases) hits 8 distinct 4-bank groups;
//    slot is k-invariant (16k + 4k = 0 mod 4). R4's stride-68 had lanes
//    l, l+8 colliding (68*8 = 0 mod 32) -> 1.57M conflict cycles.
//  - Each wave processes 2 tiles of 64 rows; ALL 16 global loads issued
//    before any LDS phase -> 2x in-flight bytes (latency/MLP was the
//    limiter: 8 waves/CU x 8 loads = 1KB in flight vs ~9KB needed).
//  - Per-wave private buffer; DS ops are in-order per wave -> no barriers.
// ---------------------------------------------------------------------------

typedef float vfloat4 __attribute__((ext_vector_type(4)));

struct CayleyTab { signed char s[16][16]; };

constexpr CayleyTab build_tab() {
    CayleyTab t{};
    for (int i = 0; i < 16; ++i) {
        for (int j = 0; j < 16; ++j) {
            int sum = 0;
            // canonical reordering swap parity: sum_k popcount((i >> (k+1)) & j)
            for (int a = i >> 1; a; a >>= 1) {
                int m = a & j;
                while (m) { sum += (m & 1); m >>= 1; }
            }
            // metric: generator 3 (bit 3) squares to -1; bits 0..2 square to +1
            sum += ((i & j) >> 3) & 1;
            t.s[i][j] = (signed char)((sum & 1) ? -1 : 1);
        }
    }
    return t;
}

constexpr CayleyTab TAB = build_tab();

__device__ __forceinline__ float clip1000(float v) {
    return fminf(fmaxf(v, -1000.0f), 1000.0f);
}

__global__ __launch_bounds__(128) void clifford_gp_kernel(
        const float* __restrict__ a,
        const float* __restrict__ b,
        float* __restrict__ out,
        int nrows) {
    __shared__ float lds[2][64 * 16];     // 2 waves x 16KB

    const int wid  = threadIdx.x >> 6;
    const int lane = threadIdx.x & 63;
    float* buf = lds[wid];

    const int R0 = (blockIdx.x * 2 + wid) * 128;   // wave owns 128 rows
    if (R0 >= nrows) return;

    const int w = lane >> 2;        // g-order row-within-16 block
    const int q = lane & 3;         // g-order quarter
    const int sW = (q + w + (w >> 2)) & 3;              // slot, k-invariant
    int sR[4];
    #pragma unroll
    for (int qq = 0; qq < 4; ++qq)
        sR[qq] = (qq + lane + (lane >> 2)) & 3;         // row-order slots

    // ---- issue ALL global loads for both tiles up front (MLP) ----
    vfloat4 pa[2][4], pb[2][4];
    #pragma unroll
    for (int t = 0; t < 2; ++t) {
        const size_t gb = (size_t)(R0 + 64 * t) * 16;
        #pragma unroll
        for (int k = 0; k < 4; ++k) {
            pa[t][k] = *reinterpret_cast<const vfloat4*>(a + gb + (size_t)(k * 64 + lane) * 4);
            pb[t][k] = *reinterpret_cast<const vfloat4*>(b + gb + (size_t)(k * 64 + lane) * 4);
        }
    }

    #pragma unroll
    for (int t = 0; t < 2; ++t) {
        const size_t gb = (size_t)(R0 + 64 * t) * 16;

        float av[16], bv[16];

        // ---- A: write g-order (swizzled), read row-order ----
        #pragma unroll
        for (int k = 0; k < 4; ++k)
            *reinterpret_cast<vfloat4*>(&buf[(16 * k + w) * 16 + sW * 4]) = pa[t][k];
        #pragma unroll
        for (int qq = 0; qq < 4; ++qq) {
            const vfloat4 v = *reinterpret_cast<const vfloat4*>(&buf[lane * 16 + sR[qq] * 4]);
            av[4 * qq + 0] = v.x; av[4 * qq + 1] = v.y;
            av[4 * qq + 2] = v.z; av[4 * qq + 3] = v.w;
        }

        // ---- B: same buffer (in-order DS per wave handles reuse) ----
        #pragma unroll
        for (int k = 0; k < 4; ++k)
            *reinterpret_cast<vfloat4*>(&buf[(16 * k + w) * 16 + sW * 4]) = pb[t][k];
        #pragma unroll
        for (int qq = 0; qq < 4; ++qq) {
            const vfloat4 v = *reinterpret_cast<const vfloat4*>(&buf[lane * 16 + sR[qq] * 4]);
            bv[4 * qq + 0] = v.x; bv[4 * qq + 1] = v.y;
            bv[4 * qq + 2] = v.z; bv[4 * qq + 3] = v.w;
        }

        // ---- 256-FMA geometric product, signs folded at compile time ----
        float acc[16];
        #pragma unroll
        for (int c = 0; c < 16; ++c) acc[c] = 0.0f;
        #pragma unroll
        for (int i = 0; i < 16; ++i) {
            #pragma unroll
            for (int j = 0; j < 16; ++j) {
                const int c = i ^ j;
                if (TAB.s[i][j] > 0) acc[c] = fmaf(av[i],  bv[j], acc[c]);
                else                 acc[c] = fmaf(av[i], -bv[j], acc[c]);
            }
        }

        // ---- out: write row-order, read g-order, store coalesced ----
        #pragma unroll
        for (int qq = 0; qq < 4; ++qq) {
            vfloat4 v;
            v.x = clip1000(acc[4 * qq + 0]);
            v.y = clip1000(acc[4 * qq + 1]);
            v.z = clip1000(acc[4 * qq + 2]);
            v.w = clip1000(acc[4 * qq + 3]);
            *reinterpret_cast<vfloat4*>(&buf[lane * 16 + sR[qq] * 4]) = v;
        }
        #pragma unroll
        for (int k = 0; k < 4; ++k) {
            const vfloat4 v = *reinterpret_cast<const vfloat4*>(&buf[(16 * k + w) * 16 + sW * 4]);
            *reinterpret_cast<vfloat4*>(out + gb + (size_t)(k * 64 + lane) * 4) = v;
        }
    }
}

extern "C" void kernel_launch(void* const* d_in, const int* in_sizes, int n_in,
                              void* d_out, int out_size, void* d_ws, size_t ws_size,
                              hipStream_t stream) {
    const float* a = (const float*)d_in[0];
    const float* b = (const float*)d_in[1];
    float* out = (float*)d_out;

    const int nrows = in_sizes[0] / 16;            // N = 1048576
    const int block = 128;                         // 2 waves x 128 rows
    const int blocks = (nrows + 255) / 256;        // 4096

    clifford_gp_kernel<<<blocks, block, 0, stream>>>(a, b, out, nrows);
}